// Round 13
// baseline (186.675 us; speedup 1.0000x reference)
//
#include <hip/hip_runtime.h>
#include <math.h>

typedef __bf16 bf16_t;
typedef __attribute__((ext_vector_type(8))) __bf16 bf16x8;
typedef __attribute__((ext_vector_type(4))) float f32x4;

#define B_  4
#define T_  2048
#define D_  1024
#define H_  16
#define HD_ 64
#define D3_ 3072

__device__ __forceinline__ void load_lds16(const bf16_t* g, char* lds) {
  __builtin_amdgcn_global_load_lds(
      (const __attribute__((address_space(1))) void*)g,
      (__attribute__((address_space(3))) void*)lds, 16, 0, 0);
}

// ---------------------------------------------------------------------------
// fp32 -> bf16 elementwise convert (vectorized)
// ---------------------------------------------------------------------------
__global__ __launch_bounds__(256) void convert_bf16(
    const float* __restrict__ in, bf16_t* __restrict__ out, int n4) {
  int idx = blockIdx.x * 256 + threadIdx.x;
  int stride = gridDim.x * 256;
  for (int i = idx; i < n4; i += stride) {
    float4 v = ((const float4*)in)[i];
    alignas(8) bf16_t o4[4] = {(bf16_t)v.x, (bf16_t)v.y, (bf16_t)v.z, (bf16_t)v.w};
    ((uint2*)out)[i] = *(const uint2*)o4;
  }
}

// ---------------------------------------------------------------------------
// W (K x N fp32) -> Wt (N x K bf16), tiled 64x64 transpose through LDS.
// ---------------------------------------------------------------------------
__global__ __launch_bounds__(256) void transpose_convert(
    const float* __restrict__ W, bf16_t* __restrict__ Wt, int K, int N) {
  __shared__ float tile[64][65];
  const int k0 = blockIdx.x * 64, n0 = blockIdx.y * 64;
  const int tid = threadIdx.x;
  const int r = tid >> 4, c4 = (tid & 15) * 4;
#pragma unroll
  for (int i = 0; i < 4; ++i) {
    float4 v = *(const float4*)(W + (size_t)(k0 + r + i * 16) * N + n0 + c4);
    tile[r + i * 16][c4 + 0] = v.x;
    tile[r + i * 16][c4 + 1] = v.y;
    tile[r + i * 16][c4 + 2] = v.z;
    tile[r + i * 16][c4 + 3] = v.w;
  }
  __syncthreads();
#pragma unroll
  for (int i = 0; i < 4; ++i) {
    int n = r + i * 16;
    alignas(8) bf16_t o4[4];
#pragma unroll
    for (int j = 0; j < 4; ++j) o4[j] = (bf16_t)tile[c4 + j][n];
    *(uint2*)(Wt + (size_t)(n0 + n) * K + k0 + c4) = *(const uint2*)o4;
  }
}

// ---------------------------------------------------------------------------
// bf16 MFMA GEMM (128x128, 2-phase dbuf) — proven; used for the proj GEMM.
// ---------------------------------------------------------------------------
#define GBM 128
#define GBN 128
#define GBK 32

template <bool BF16_OUT>
__global__ __launch_bounds__(256) void gemm_bt_mfma(
    const bf16_t* __restrict__ A, const bf16_t* __restrict__ Bt,
    const float* __restrict__ bias, void* __restrict__ Cv,
    int M, int N, int K) {
  __shared__ __align__(16) bf16_t Asl[2][GBM * GBK];
  __shared__ __align__(16) bf16_t Bsl[2][GBN * GBK];

  const int tid = threadIdx.x;
  const int w = tid >> 6, l = tid & 63;
  const int l15 = l & 15, lhi = l >> 4;
  const int row0 = blockIdx.y * GBM, col0 = blockIdx.x * GBN;
  const int wr = (w >> 1) * 64, wc = (w & 1) * 64;

  const int srow = tid >> 2;
  const int sf = (srow & 3) ^ ((srow >> 2) & 3);
  const int slog = (tid & 3) ^ sf;
  const int rf = (l15 & 3) ^ ((l15 >> 2) & 3);
  const int rchunk = lhi ^ rf;

  f32x4 acc[4][4];
#pragma unroll
  for (int i = 0; i < 4; ++i)
#pragma unroll
    for (int j = 0; j < 4; ++j) acc[i][j] = (f32x4){0.f, 0.f, 0.f, 0.f};

  const bf16_t* Abase = A + (size_t)row0 * K;
  const bf16_t* Bbase = Bt + (size_t)col0 * K;

  auto stage = [&](int buf, int k0) {
#pragma unroll
    for (int issue = 0; issue < 2; ++issue) {
      const bf16_t* ga = Abase + (size_t)(issue * 64 + srow) * K + k0 + slog * 8;
      load_lds16(ga, (char*)&Asl[buf][0] + issue * 4096 + w * 1024);
      const bf16_t* gb = Bbase + (size_t)(issue * 64 + srow) * K + k0 + slog * 8;
      load_lds16(gb, (char*)&Bsl[buf][0] + issue * 4096 + w * 1024);
    }
  };

  const int nt = K / GBK;
  stage(0, 0);

  for (int t = 0; t < nt; ++t) {
    __syncthreads();
    if (t + 1 < nt) stage((t + 1) & 1, (t + 1) * GBK);

    const bf16_t* As = &Asl[t & 1][0];
    const bf16_t* Bs = &Bsl[t & 1][0];
    bf16x8 af[4], bf[4];
#pragma unroll
    for (int i = 0; i < 4; ++i)
      af[i] = *(const bf16x8*)&As[(wr + i * 16 + l15) * GBK + rchunk * 8];
#pragma unroll
    for (int j = 0; j < 4; ++j)
      bf[j] = *(const bf16x8*)&Bs[(wc + j * 16 + l15) * GBK + rchunk * 8];
#pragma unroll
    for (int i = 0; i < 4; ++i)
#pragma unroll
      for (int j = 0; j < 4; ++j)
        acc[i][j] =
            __builtin_amdgcn_mfma_f32_16x16x32_bf16(af[i], bf[j], acc[i][j], 0, 0, 0);
  }

#pragma unroll
  for (int j = 0; j < 4; ++j) {
    int colr = col0 + wc + j * 16 + l15;
    float bv = bias[colr];
#pragma unroll
    for (int i = 0; i < 4; ++i) {
#pragma unroll
      for (int r = 0; r < 4; ++r) {
        int rowr = row0 + wr + i * 16 + lhi * 4 + r;
        float val = acc[i][j][r] + bv;
        if constexpr (BF16_OUT)
          ((bf16_t*)Cv)[(size_t)rowr * N + colr] = (bf16_t)val;
        else
          ((float*)Cv)[(size_t)rowr * N + colr] = val;
      }
    }
  }
}

// ---------------------------------------------------------------------------
// R13: 256x256-tile bf16 GEMM, 8 waves (2M x 4N, 128x64 per wave), BK=32.
// 4-buffer LDS (128 KB), distance-3 prefetch, counted vmcnt(8) + raw
// s_barrier ONCE per K-tile (loads issued 3 tiles early stay in flight
// across barriers), 2 MFMA phases per tile (16 MFMA between barriers).
// Ledger: 4 loads/thread/tile (2A+2B), uniform via tail-clamp into dead
// buffers (mod-4: buf[(t+3)&3] is never among buf[t..t+2]). RAW: per-wave
// vmcnt(8) + barrier => all waves' tile-t loads landed. WAR: a buffer is
// rewritten 4 tiles after its reads (consumed via lgkmcnt before MFMAs
// that precede >=2 intervening barriers). bf16 output.
// ---------------------------------------------------------------------------
#define QBM 256
#define QBN 256
#define QBK 32

__global__ __launch_bounds__(512, 1) void gemm_bt_256(
    const bf16_t* __restrict__ A, const bf16_t* __restrict__ Bt,
    const float* __restrict__ bias, bf16_t* __restrict__ C,
    int M, int N, int K) {
  __shared__ __align__(16) bf16_t Asl[4][QBM * QBK];  // 4 x 16 KB
  __shared__ __align__(16) bf16_t Bsl[4][QBN * QBK];  // 4 x 16 KB

  const int tid = threadIdx.x;
  const int l = tid & 63;
  const int l15 = l & 15, lhi = l >> 4;
  const int w = tid >> 6;
  const int wm = w >> 2, wn = w & 3;  // 2 x 4 wave grid
  const int row0 = blockIdx.y * QBM, col0 = blockIdx.x * QBN;

  // staging map (proven swizzle; sf is issue-invariant since issue adds 128)
  const int srow = tid >> 2;  // 0..127
  const int sf = (srow & 3) ^ ((srow >> 2) & 3);
  const int slog = (tid & 3) ^ sf;
  const int rf = (l15 & 3) ^ ((l15 >> 2) & 3);
  const int rchunk = lhi ^ rf;

  f32x4 acc[8][4];
#pragma unroll
  for (int i = 0; i < 8; ++i)
#pragma unroll
    for (int j = 0; j < 4; ++j) acc[i][j] = (f32x4){0.f, 0.f, 0.f, 0.f};

  const bf16_t* Abase = A + (size_t)row0 * K;
  const bf16_t* Bbase = Bt + (size_t)col0 * K;

  auto stageA = [&](int buf, int k0) {
#pragma unroll
    for (int i = 0; i < 2; ++i) {
      const bf16_t* g = Abase + (size_t)(i * 128 + srow) * K + k0 + slog * 8;
      load_lds16(g, (char*)&Asl[buf][0] + i * 8192 + tid * 16);
    }
  };
  auto stageB = [&](int buf, int k0) {
#pragma unroll
    for (int i = 0; i < 2; ++i) {
      const bf16_t* g = Bbase + (size_t)(i * 128 + srow) * K + k0 + slog * 8;
      load_lds16(g, (char*)&Bsl[buf][0] + i * 8192 + tid * 16);
    }
  };

  const int nt = K / QBK;
  // prologue: tiles 0,1,2 staged (12 loads; per-tile order A,A,B,B = steady)
  stageA(0, 0);
  stageB(0, 0);
  stageA(1, QBK);
  stageB(1, QBK);
  stageA(2, 2 * QBK);
  stageB(2, 2 * QBK);

  for (int t = 0; t < nt; ++t) {
    // tile top: this wave's tile-t loads (issued 3 tiles ago) landed when
    // outstanding <= 8 (= tiles t+1,t+2); barrier makes it true for ALL waves.
    asm volatile("s_waitcnt vmcnt(8)" ::: "memory");
    __builtin_amdgcn_s_barrier();
    asm volatile("" ::: "memory");

    const bf16_t* As = &Asl[t & 3][0];
    const bf16_t* Bs = &Bsl[t & 3][0];
    const int t3 = t + 3;
    const int ks = (t3 < nt ? t3 : nt - 1) * QBK;  // clamp: uniform ledger
    const int b3 = t3 & 3;                          // dead buffer at tail

    // ---- phase 0: B-frags + A row-tiles 0..3 ----
    bf16x8 bfr[4], af[4];
#pragma unroll
    for (int j = 0; j < 4; ++j)
      bfr[j] = *(const bf16x8*)&Bs[(wn * 64 + j * 16 + l15) * QBK + rchunk * 8];
#pragma unroll
    for (int i = 0; i < 4; ++i)
      af[i] = *(const bf16x8*)&As[(wm * 128 + i * 16 + l15) * QBK + rchunk * 8];
    stageA(b3, ks);
    __builtin_amdgcn_s_setprio(1);
#pragma unroll
    for (int i = 0; i < 4; ++i)
#pragma unroll
      for (int j = 0; j < 4; ++j)
        acc[i][j] =
            __builtin_amdgcn_mfma_f32_16x16x32_bf16(af[i], bfr[j], acc[i][j], 0, 0, 0);
    __builtin_amdgcn_s_setprio(0);
    __builtin_amdgcn_s_barrier();
    asm volatile("" ::: "memory");

    // ---- phase 1: A row-tiles 4..7 ----
#pragma unroll
    for (int i = 0; i < 4; ++i)
      af[i] =
          *(const bf16x8*)&As[(wm * 128 + (i + 4) * 16 + l15) * QBK + rchunk * 8];
    stageB(b3, ks);
    __builtin_amdgcn_s_setprio(1);
#pragma unroll
    for (int i = 0; i < 4; ++i)
#pragma unroll
      for (int j = 0; j < 4; ++j)
        acc[i + 4][j] =
            __builtin_amdgcn_mfma_f32_16x16x32_bf16(af[i], bfr[j], acc[i + 4][j], 0, 0, 0);
    __builtin_amdgcn_s_setprio(0);
    asm volatile("" ::: "memory");
    // next tile-top barrier closes the phase
  }

  // epilogue: C/D layout col=l&15, row=(l>>4)*4+reg
#pragma unroll
  for (int j = 0; j < 4; ++j) {
    int colr = col0 + wn * 64 + j * 16 + l15;
    float bv = bias[colr];
#pragma unroll
    for (int i = 0; i < 8; ++i) {
#pragma unroll
      for (int r = 0; r < 4; ++r) {
        int rowr = row0 + wm * 128 + i * 16 + lhi * 4 + r;
        C[(size_t)rowr * N + colr] = (bf16_t)(acc[i][j][r] + bv);
      }
    }
  }
}

// ---------------------------------------------------------------------------
// Transpose V out of qkv_bf into Vg[bh][d][t] (bf16).
// ---------------------------------------------------------------------------
__global__ __launch_bounds__(256) void transpose_v(
    const bf16_t* __restrict__ qkv, bf16_t* __restrict__ Vg) {
  const int bh = blockIdx.y;
  const int b = bh >> 4, h = bh & 15;
  const int t0 = blockIdx.x * 64;
  const int tid = threadIdx.x;
  const int d = tid & 63;
  const int w = tid >> 6;
  alignas(16) bf16_t tmp[16];
#pragma unroll
  for (int j = 0; j < 16; ++j) {
    int t = t0 + w * 16 + j;
    tmp[j] = qkv[(size_t)(b * T_ + t) * D3_ + 2 * D_ + h * HD_ + d];
  }
  bf16_t* dst = Vg + (size_t)(bh * HD_ + d) * T_ + t0 + w * 16;
  *(uint4*)(dst) = *(const uint4*)(tmp);
  *(uint4*)(dst + 8) = *(const uint4*)(tmp + 8);
}

// ---------------------------------------------------------------------------
// Causal flash attention (R12 form, unchanged): swapped-QK^T 16x16x32 MFMA,
// 4 waves / QBLK=128, 2-barrier staged loop, fixed-max softmax (c=8).
// ---------------------------------------------------------------------------
#define QBLK 128
#define KBLK 64

__global__ __launch_bounds__(256, 4) void attn_fwd_mfma(
    const bf16_t* __restrict__ qkv, const bf16_t* __restrict__ Vg,
    bf16_t* __restrict__ y) {
  const int lin = blockIdx.x;
  const int bh = (lin & 7) * 8 + ((lin >> 3) & 7);  // XCD-local heads
  const int qt = (T_ / QBLK - 1) - (lin >> 6);      // tail-first
  const int b = bh >> 4, h = bh & 15;
  const int Q0 = qt * QBLK;
  const int tid = threadIdx.x;
  const int w = tid >> 6, l = tid & 63;
  const int l15 = l & 15, lhi = l >> 4;

  __shared__ __align__(16) bf16_t K_lds[2][KBLK * 64];
  __shared__ __align__(16) bf16_t V_lds[KBLK * 64];
  __shared__ __align__(16) bf16_t P_lds[4][16][72];

  const int sr = tid >> 3, sp = tid & 7;
  const int slc = sp ^ (sr & 7);
  const int swz = (l15 & 7);

  auto stageK = [&](int buf, int kt) {
    const bf16_t* src =
        qkv + (size_t)(b * T_ + kt * KBLK + sr) * D3_ + D_ + h * HD_ + slc * 8;
    char* dst = (char*)(&K_lds[buf][0]) + w * 1024;
    load_lds16(src, dst);
    load_lds16(src + (size_t)32 * D3_, dst + 4096);
  };
  auto stageV = [&](int kt) {
    const bf16_t* src = Vg + ((size_t)bh * HD_ + sr) * T_ + kt * KBLK + slc * 8;
    char* dst = (char*)(&V_lds[0]) + w * 1024;
    load_lds16(src, dst);
    load_lds16(src + (size_t)32 * T_, dst + 4096);
  };

  bf16x8 qf[2][2];
#pragma unroll
  for (int g = 0; g < 2; ++g) {
    int q = Q0 + w * 32 + g * 16 + l15;
#pragma unroll
    for (int c = 0; c < 2; ++c) {
      const bf16_t* p = qkv + (size_t)(b * T_ + q) * D3_ + h * HD_ + c * 32 + lhi * 8;
      bf16x8 v = *(const bf16x8*)p;
#pragma unroll
      for (int e = 0; e < 8; ++e) v[e] = (bf16_t)((float)v[e] * 0.125f);
      qf[g][c] = v;
    }
  }

  f32x4 accO[2][4];
#pragma unroll
  for (int g = 0; g < 2; ++g)
#pragma unroll
    for (int dg = 0; dg < 4; ++dg) accO[g][dg] = (f32x4){0.f, 0.f, 0.f, 0.f};
  float lsum[2] = {0.f, 0.f};
  const float FMAX = 8.f;

  const int ntiles = Q0 / KBLK + 2;
  const int qg0 = Q0 + w * 32;
  const int qg1 = qg0 + 16;

  stageK(0, 0);
  __syncthreads();

  for (int kt = 0; kt < ntiles; ++kt) {
    const int cur = kt & 1;
    const int ktb = kt * KBLK;
    stageV(kt);
    if (kt + 1 < ntiles) stageK(cur ^ 1, kt + 1);

    const bool act0 = (ktb <= qg0 + 15);
    const bool act1 = (ktb <= qg1 + 15);
    uint2 pp1[4];

#pragma unroll
    for (int g = 0; g < 2; ++g) {
      if (!(g == 0 ? act0 : act1)) continue;
      const int qg = g == 0 ? qg0 : qg1;

      f32x4 s[4];
#pragma unroll
      for (int n = 0; n < 4; ++n) s[n] = (f32x4){0.f, 0.f, 0.f, 0.f};
      __builtin_amdgcn_s_setprio(1);
#pragma unroll
      for (int c = 0; c < 2; ++c) {
#pragma unroll
        for (int n = 0; n < 4; ++n) {
          bf16x8 kf = *(const bf16x8*)&K_lds[cur][(n * 16 + l15) * 64 +
                                                 (((c * 4 + lhi) ^ swz) * 8)];
          s[n] = __builtin_amdgcn_mfma_f32_16x16x32_bf16(kf, qf[g][c], s[n], 0, 0, 0);
        }
      }
      __builtin_amdgcn_s_setprio(0);

      if (ktb + KBLK - 1 > qg) {
        const int qml = qg + l15 - ktb - lhi * 4;
#pragma unroll
        for (int n = 0; n < 4; ++n)
#pragma unroll
          for (int r = 0; r < 4; ++r)
            if (n * 16 + r > qml) s[n][r] = -INFINITY;
      }

      float rowsum = 0.f;
#pragma unroll
      for (int n = 0; n < 4; ++n) {
        alignas(8) bf16_t p4[4];
#pragma unroll
        for (int r = 0; r < 4; ++r) {
          float p = __expf(s[n][r] - FMAX);
          rowsum += p;
          p4[r] = (bf16_t)p;
        }
        if (g == 0)
          *(uint2*)&P_lds[w][l15][n * 16 + lhi * 4] = *(const uint2*)p4;
        else
          pp1[n] = *(const uint2*)p4;
      }
      lsum[g] += rowsum;
    }

    __syncthreads();

    if (act0) {
      __builtin_amdgcn_s_setprio(1);
#pragma unroll
      for (int c2 = 0; c2 < 2; ++c2) {
        bf16x8 pf = *(const bf16x8*)&P_lds[w][l15][c2 * 32 + lhi * 8];
#pragma unroll
        for (int dg = 0; dg < 4; ++dg) {
          bf16x8 vf = *(const bf16x8*)&V_lds[(dg * 16 + l15) * 64 +
                                             (((c2 * 4 + lhi) ^ swz) * 8)];
          accO[0][dg] =
              __builtin_amdgcn_mfma_f32_16x16x32_bf16(pf, vf, accO[0][dg], 0, 0, 0);
        }
      }
      __builtin_amdgcn_s_setprio(0);
    }
    if (act1) {
#pragma unroll
      for (int n = 0; n < 4; ++n)
        *(uint2*)&P_lds[w][l15][n * 16 + lhi * 4] = pp1[n];
      __builtin_amdgcn_s_setprio(1);
#pragma unroll
      for (int c2 = 0; c2 < 2; ++c2) {
        bf16x8 pf = *(const bf16x8*)&P_lds[w][l15][c2 * 32 + lhi * 8];
#pragma unroll
        for (int dg = 0; dg < 4; ++dg) {
          bf16x8 vf = *(const bf16x8*)&V_lds[(dg * 16 + l15) * 64 +
                                             (((c2 * 4 + lhi) ^ swz) * 8)];
          accO[1][dg] =
              __builtin_amdgcn_mfma_f32_16x16x32_bf16(pf, vf, accO[1][dg], 0, 0, 0);
        }
      }
      __builtin_amdgcn_s_setprio(0);
    }

    __syncthreads();
  }

#pragma unroll
  for (int g = 0; g < 2; ++g) {
    float ls = lsum[g];
    ls += __shfl_xor(ls, 16);
    ls += __shfl_xor(ls, 32);
#pragma unroll
    for (int r = 0; r < 4; ++r) {
      float lr = __shfl(ls, lhi * 4 + r);
      float inv = 1.f / lr;
      int q = Q0 + w * 32 + g * 16 + lhi * 4 + r;
      bf16_t* yr = y + (size_t)(b * T_ + q) * D_ + h * HD_ + l15;
#pragma unroll
      for (int dg = 0; dg < 4; ++dg) yr[dg * 16] = (bf16_t)(accO[g][dg][r] * inv);
    }
  }
}

// ---------------------------------------------------------------------------
extern "C" void kernel_launch(void* const* d_in, const int* in_sizes, int n_in,
                              void* d_out, int out_size, void* d_ws, size_t ws_size,
                              hipStream_t stream) {
  const float* x      = (const float*)d_in[0];
  const float* w_attn = (const float*)d_in[1];
  const float* b_attn = (const float*)d_in[2];
  const float* w_proj = (const float*)d_in[3];
  const float* b_proj = (const float*)d_in[4];
  float* out = (float*)d_out;

  const int M = B_ * T_;  // 8192

  bf16_t* xb      = (bf16_t*)d_ws;                         // 16 MB (reused as y_bf)
  bf16_t* wattnT  = xb + (size_t)M * D_;                   // 6 MB
  bf16_t* wprojT  = wattnT + (size_t)D3_ * D_;             // 2 MB
  bf16_t* qkv_bf  = wprojT + (size_t)D_ * D_;              // 48 MB
  bf16_t* Vg      = qkv_bf + (size_t)M * D3_;              // 16 MB
  bf16_t* y_bf    = xb;

  convert_bf16<<<2048, 256, 0, stream>>>(x, xb, M * D_ / 4);
  transpose_convert<<<dim3(D_ / 64, D3_ / 64), 256, 0, stream>>>(w_attn, wattnT, D_, D3_);
  transpose_convert<<<dim3(D_ / 64, D_ / 64), 256, 0, stream>>>(w_proj, wprojT, D_, D_);
  // QKV GEMM: new 256^2 counted-vmcnt kernel (bf16 out)
  gemm_bt_256<<<dim3(D3_ / QBN, M / QBM), 512, 0, stream>>>(
      xb, wattnT, b_attn, qkv_bf, M, D3_, D_);
  transpose_v<<<dim3(T_ / 64, B_ * H_), 256, 0, stream>>>(qkv_bf, Vg);
  attn_fwd_mfma<<<dim3(T_ / QBLK * B_ * H_), 256, 0, stream>>>(qkv_bf, Vg, y_bf);
  // proj GEMM: proven 128^2 kernel (fp32 out)
  gemm_bt_mfma<false><<<dim3(D_ / GBN, M / GBM), 256, 0, stream>>>(
      y_bf, wprojT, b_proj, out, M, D_, D_);
}

// Round 14
// 185.334 us; speedup vs baseline: 1.0072x; 1.0072x over previous
//
#include <hip/hip_runtime.h>
#include <math.h>

typedef __bf16 bf16_t;
typedef __attribute__((ext_vector_type(8))) __bf16 bf16x8;
typedef __attribute__((ext_vector_type(4))) float f32x4;

#define B_  4
#define T_  2048
#define D_  1024
#define H_  16
#define HD_ 64
#define D3_ 3072

__device__ __forceinline__ void load_lds16(const bf16_t* g, char* lds) {
  __builtin_amdgcn_global_load_lds(
      (const __attribute__((address_space(1))) void*)g,
      (__attribute__((address_space(3))) void*)lds, 16, 0, 0);
}

// ---------------------------------------------------------------------------
// fp32 -> bf16 elementwise convert (vectorized)
// ---------------------------------------------------------------------------
__global__ __launch_bounds__(256) void convert_bf16(
    const float* __restrict__ in, bf16_t* __restrict__ out, int n4) {
  int idx = blockIdx.x * 256 + threadIdx.x;
  int stride = gridDim.x * 256;
  for (int i = idx; i < n4; i += stride) {
    float4 v = ((const float4*)in)[i];
    alignas(8) bf16_t o4[4] = {(bf16_t)v.x, (bf16_t)v.y, (bf16_t)v.z, (bf16_t)v.w};
    ((uint2*)out)[i] = *(const uint2*)o4;
  }
}

// ---------------------------------------------------------------------------
// W (K x N fp32) -> Wt (N x K bf16), tiled 64x64 transpose through LDS.
// ---------------------------------------------------------------------------
__global__ __launch_bounds__(256) void transpose_convert(
    const float* __restrict__ W, bf16_t* __restrict__ Wt, int K, int N) {
  __shared__ float tile[64][65];
  const int k0 = blockIdx.x * 64, n0 = blockIdx.y * 64;
  const int tid = threadIdx.x;
  const int r = tid >> 4, c4 = (tid & 15) * 4;
#pragma unroll
  for (int i = 0; i < 4; ++i) {
    float4 v = *(const float4*)(W + (size_t)(k0 + r + i * 16) * N + n0 + c4);
    tile[r + i * 16][c4 + 0] = v.x;
    tile[r + i * 16][c4 + 1] = v.y;
    tile[r + i * 16][c4 + 2] = v.z;
    tile[r + i * 16][c4 + 3] = v.w;
  }
  __syncthreads();
#pragma unroll
  for (int i = 0; i < 4; ++i) {
    int n = r + i * 16;
    alignas(8) bf16_t o4[4];
#pragma unroll
    for (int j = 0; j < 4; ++j) o4[j] = (bf16_t)tile[c4 + j][n];
    *(uint2*)(Wt + (size_t)(n0 + n) * K + k0 + c4) = *(const uint2*)o4;
  }
}

// ---------------------------------------------------------------------------
// bf16 MFMA GEMM (128x128, 2-phase dbuf) — proven structure (R5/R12).
// R14: optional fused V-transpose output. If Vg != nullptr, output blocks in
// the V column range (col0 >= 2*D) are written TRANSPOSED into
// Vg[bh][d][t] (8B packed stores; lane holds 4 consecutive t per (i,j))
// instead of into C — the separate transpose_v kernel is deleted, and the
// V third of qkv is never written (nothing reads it).
// ---------------------------------------------------------------------------
#define GBM 128
#define GBN 128
#define GBK 32

template <bool BF16_OUT>
__global__ __launch_bounds__(256) void gemm_bt_mfma(
    const bf16_t* __restrict__ A, const bf16_t* __restrict__ Bt,
    const float* __restrict__ bias, void* __restrict__ Cv,
    bf16_t* __restrict__ Vg,  // nullptr: plain GEMM
    int M, int N, int K) {
  __shared__ __align__(16) bf16_t Asl[2][GBM * GBK];
  __shared__ __align__(16) bf16_t Bsl[2][GBN * GBK];

  const int tid = threadIdx.x;
  const int w = tid >> 6, l = tid & 63;
  const int l15 = l & 15, lhi = l >> 4;
  const int row0 = blockIdx.y * GBM, col0 = blockIdx.x * GBN;
  const int wr = (w >> 1) * 64, wc = (w & 1) * 64;

  const int srow = tid >> 2;
  const int sf = (srow & 3) ^ ((srow >> 2) & 3);
  const int slog = (tid & 3) ^ sf;
  const int rf = (l15 & 3) ^ ((l15 >> 2) & 3);
  const int rchunk = lhi ^ rf;

  f32x4 acc[4][4];
#pragma unroll
  for (int i = 0; i < 4; ++i)
#pragma unroll
    for (int j = 0; j < 4; ++j) acc[i][j] = (f32x4){0.f, 0.f, 0.f, 0.f};

  const bf16_t* Abase = A + (size_t)row0 * K;
  const bf16_t* Bbase = Bt + (size_t)col0 * K;

  auto stage = [&](int buf, int k0) {
#pragma unroll
    for (int issue = 0; issue < 2; ++issue) {
      const bf16_t* ga = Abase + (size_t)(issue * 64 + srow) * K + k0 + slog * 8;
      load_lds16(ga, (char*)&Asl[buf][0] + issue * 4096 + w * 1024);
      const bf16_t* gb = Bbase + (size_t)(issue * 64 + srow) * K + k0 + slog * 8;
      load_lds16(gb, (char*)&Bsl[buf][0] + issue * 4096 + w * 1024);
    }
  };

  const int nt = K / GBK;
  stage(0, 0);

  for (int t = 0; t < nt; ++t) {
    __syncthreads();
    if (t + 1 < nt) stage((t + 1) & 1, (t + 1) * GBK);

    const bf16_t* As = &Asl[t & 1][0];
    const bf16_t* Bs = &Bsl[t & 1][0];
    bf16x8 af[4], bf[4];
#pragma unroll
    for (int i = 0; i < 4; ++i)
      af[i] = *(const bf16x8*)&As[(wr + i * 16 + l15) * GBK + rchunk * 8];
#pragma unroll
    for (int j = 0; j < 4; ++j)
      bf[j] = *(const bf16x8*)&Bs[(wc + j * 16 + l15) * GBK + rchunk * 8];
#pragma unroll
    for (int i = 0; i < 4; ++i)
#pragma unroll
      for (int j = 0; j < 4; ++j)
        acc[i][j] =
            __builtin_amdgcn_mfma_f32_16x16x32_bf16(af[i], bf[j], acc[i][j], 0, 0, 0);
  }

  // epilogue: C/D layout col=l&15, row=(l>>4)*4+reg
  if (Vg != nullptr && col0 >= 2 * D_) {
    // V block: write transposed into Vg[bh][d][t] (t = row within batch).
    const int bq = row0 >> 11;  // batch index (T = 2048; 128 | T so no spill)
#pragma unroll
    for (int j = 0; j < 4; ++j) {
      int colr = col0 + wc + j * 16 + l15;
      int dcol = colr - 2 * D_;
      int bh = bq * 16 + (dcol >> 6);
      int d = dcol & 63;
      float bv = bias[colr];
      bf16_t* vbase = Vg + ((size_t)bh * HD_ + d) * T_;
#pragma unroll
      for (int i = 0; i < 4; ++i) {
        int t0 = (row0 & (T_ - 1)) + wr + i * 16 + lhi * 4;
        alignas(8) bf16_t p4[4];
#pragma unroll
        for (int r = 0; r < 4; ++r) p4[r] = (bf16_t)(acc[i][j][r] + bv);
        *(uint2*)(vbase + t0) = *(const uint2*)p4;
      }
    }
  } else {
#pragma unroll
    for (int j = 0; j < 4; ++j) {
      int colr = col0 + wc + j * 16 + l15;
      float bv = bias[colr];
#pragma unroll
      for (int i = 0; i < 4; ++i) {
#pragma unroll
        for (int r = 0; r < 4; ++r) {
          int rowr = row0 + wr + i * 16 + lhi * 4 + r;
          float val = acc[i][j][r] + bv;
          if constexpr (BF16_OUT)
            ((bf16_t*)Cv)[(size_t)rowr * N + colr] = (bf16_t)val;
          else
            ((float*)Cv)[(size_t)rowr * N + colr] = val;
        }
      }
    }
  }
}

// ---------------------------------------------------------------------------
// Causal flash attention (R12 form, unchanged): swapped-QK^T 16x16x32 MFMA,
// 4 waves / QBLK=128, 2-barrier staged loop, fixed-max softmax (c=8).
// ---------------------------------------------------------------------------
#define QBLK 128
#define KBLK 64

__global__ __launch_bounds__(256, 4) void attn_fwd_mfma(
    const bf16_t* __restrict__ qkv, const bf16_t* __restrict__ Vg,
    bf16_t* __restrict__ y) {
  const int lin = blockIdx.x;
  const int bh = (lin & 7) * 8 + ((lin >> 3) & 7);  // XCD-local heads
  const int qt = (T_ / QBLK - 1) - (lin >> 6);      // tail-first
  const int b = bh >> 4, h = bh & 15;
  const int Q0 = qt * QBLK;
  const int tid = threadIdx.x;
  const int w = tid >> 6, l = tid & 63;
  const int l15 = l & 15, lhi = l >> 4;

  __shared__ __align__(16) bf16_t K_lds[2][KBLK * 64];
  __shared__ __align__(16) bf16_t V_lds[KBLK * 64];
  __shared__ __align__(16) bf16_t P_lds[4][16][72];

  const int sr = tid >> 3, sp = tid & 7;
  const int slc = sp ^ (sr & 7);
  const int swz = (l15 & 7);

  auto stageK = [&](int buf, int kt) {
    const bf16_t* src =
        qkv + (size_t)(b * T_ + kt * KBLK + sr) * D3_ + D_ + h * HD_ + slc * 8;
    char* dst = (char*)(&K_lds[buf][0]) + w * 1024;
    load_lds16(src, dst);
    load_lds16(src + (size_t)32 * D3_, dst + 4096);
  };
  auto stageV = [&](int kt) {
    const bf16_t* src = Vg + ((size_t)bh * HD_ + sr) * T_ + kt * KBLK + slc * 8;
    char* dst = (char*)(&V_lds[0]) + w * 1024;
    load_lds16(src, dst);
    load_lds16(src + (size_t)32 * T_, dst + 4096);
  };

  bf16x8 qf[2][2];
#pragma unroll
  for (int g = 0; g < 2; ++g) {
    int q = Q0 + w * 32 + g * 16 + l15;
#pragma unroll
    for (int c = 0; c < 2; ++c) {
      const bf16_t* p = qkv + (size_t)(b * T_ + q) * D3_ + h * HD_ + c * 32 + lhi * 8;
      bf16x8 v = *(const bf16x8*)p;
#pragma unroll
      for (int e = 0; e < 8; ++e) v[e] = (bf16_t)((float)v[e] * 0.125f);
      qf[g][c] = v;
    }
  }

  f32x4 accO[2][4];
#pragma unroll
  for (int g = 0; g < 2; ++g)
#pragma unroll
    for (int dg = 0; dg < 4; ++dg) accO[g][dg] = (f32x4){0.f, 0.f, 0.f, 0.f};
  float lsum[2] = {0.f, 0.f};
  const float FMAX = 8.f;

  const int ntiles = Q0 / KBLK + 2;
  const int qg0 = Q0 + w * 32;
  const int qg1 = qg0 + 16;

  stageK(0, 0);
  __syncthreads();

  for (int kt = 0; kt < ntiles; ++kt) {
    const int cur = kt & 1;
    const int ktb = kt * KBLK;
    stageV(kt);
    if (kt + 1 < ntiles) stageK(cur ^ 1, kt + 1);

    const bool act0 = (ktb <= qg0 + 15);
    const bool act1 = (ktb <= qg1 + 15);
    uint2 pp1[4];

#pragma unroll
    for (int g = 0; g < 2; ++g) {
      if (!(g == 0 ? act0 : act1)) continue;
      const int qg = g == 0 ? qg0 : qg1;

      f32x4 s[4];
#pragma unroll
      for (int n = 0; n < 4; ++n) s[n] = (f32x4){0.f, 0.f, 0.f, 0.f};
      __builtin_amdgcn_s_setprio(1);
#pragma unroll
      for (int c = 0; c < 2; ++c) {
#pragma unroll
        for (int n = 0; n < 4; ++n) {
          bf16x8 kf = *(const bf16x8*)&K_lds[cur][(n * 16 + l15) * 64 +
                                                 (((c * 4 + lhi) ^ swz) * 8)];
          s[n] = __builtin_amdgcn_mfma_f32_16x16x32_bf16(kf, qf[g][c], s[n], 0, 0, 0);
        }
      }
      __builtin_amdgcn_s_setprio(0);

      if (ktb + KBLK - 1 > qg) {
        const int qml = qg + l15 - ktb - lhi * 4;
#pragma unroll
        for (int n = 0; n < 4; ++n)
#pragma unroll
          for (int r = 0; r < 4; ++r)
            if (n * 16 + r > qml) s[n][r] = -INFINITY;
      }

      float rowsum = 0.f;
#pragma unroll
      for (int n = 0; n < 4; ++n) {
        alignas(8) bf16_t p4[4];
#pragma unroll
        for (int r = 0; r < 4; ++r) {
          float p = __expf(s[n][r] - FMAX);
          rowsum += p;
          p4[r] = (bf16_t)p;
        }
        if (g == 0)
          *(uint2*)&P_lds[w][l15][n * 16 + lhi * 4] = *(const uint2*)p4;
        else
          pp1[n] = *(const uint2*)p4;
      }
      lsum[g] += rowsum;
    }

    __syncthreads();

    if (act0) {
      __builtin_amdgcn_s_setprio(1);
#pragma unroll
      for (int c2 = 0; c2 < 2; ++c2) {
        bf16x8 pf = *(const bf16x8*)&P_lds[w][l15][c2 * 32 + lhi * 8];
#pragma unroll
        for (int dg = 0; dg < 4; ++dg) {
          bf16x8 vf = *(const bf16x8*)&V_lds[(dg * 16 + l15) * 64 +
                                             (((c2 * 4 + lhi) ^ swz) * 8)];
          accO[0][dg] =
              __builtin_amdgcn_mfma_f32_16x16x32_bf16(pf, vf, accO[0][dg], 0, 0, 0);
        }
      }
      __builtin_amdgcn_s_setprio(0);
    }
    if (act1) {
#pragma unroll
      for (int n = 0; n < 4; ++n)
        *(uint2*)&P_lds[w][l15][n * 16 + lhi * 4] = pp1[n];
      __builtin_amdgcn_s_setprio(1);
#pragma unroll
      for (int c2 = 0; c2 < 2; ++c2) {
        bf16x8 pf = *(const bf16x8*)&P_lds[w][l15][c2 * 32 + lhi * 8];
#pragma unroll
        for (int dg = 0; dg < 4; ++dg) {
          bf16x8 vf = *(const bf16x8*)&V_lds[(dg * 16 + l15) * 64 +
                                             (((c2 * 4 + lhi) ^ swz) * 8)];
          accO[1][dg] =
              __builtin_amdgcn_mfma_f32_16x16x32_bf16(pf, vf, accO[1][dg], 0, 0, 0);
        }
      }
      __builtin_amdgcn_s_setprio(0);
    }

    __syncthreads();
  }

#pragma unroll
  for (int g = 0; g < 2; ++g) {
    float ls = lsum[g];
    ls += __shfl_xor(ls, 16);
    ls += __shfl_xor(ls, 32);
#pragma unroll
    for (int r = 0; r < 4; ++r) {
      float lr = __shfl(ls, lhi * 4 + r);
      float inv = 1.f / lr;
      int q = Q0 + w * 32 + g * 16 + lhi * 4 + r;
      bf16_t* yr = y + (size_t)(b * T_ + q) * D_ + h * HD_ + l15;
#pragma unroll
      for (int dg = 0; dg < 4; ++dg) yr[dg * 16] = (bf16_t)(accO[g][dg][r] * inv);
    }
  }
}

// ---------------------------------------------------------------------------
extern "C" void kernel_launch(void* const* d_in, const int* in_sizes, int n_in,
                              void* d_out, int out_size, void* d_ws, size_t ws_size,
                              hipStream_t stream) {
  const float* x      = (const float*)d_in[0];
  const float* w_attn = (const float*)d_in[1];
  const float* b_attn = (const float*)d_in[2];
  const float* w_proj = (const float*)d_in[3];
  const float* b_proj = (const float*)d_in[4];
  float* out = (float*)d_out;

  const int M = B_ * T_;  // 8192

  bf16_t* xb      = (bf16_t*)d_ws;                         // 16 MB (reused as y_bf)
  bf16_t* wattnT  = xb + (size_t)M * D_;                   // 6 MB
  bf16_t* wprojT  = wattnT + (size_t)D3_ * D_;             // 2 MB
  bf16_t* qkv_bf  = wprojT + (size_t)D_ * D_;              // 48 MB (V third unused)
  bf16_t* Vg      = qkv_bf + (size_t)M * D3_;              // 16 MB
  bf16_t* y_bf    = xb;

  convert_bf16<<<2048, 256, 0, stream>>>(x, xb, M * D_ / 4);
  transpose_convert<<<dim3(D_ / 64, D3_ / 64), 256, 0, stream>>>(w_attn, wattnT, D_, D3_);
  transpose_convert<<<dim3(D_ / 64, D_ / 64), 256, 0, stream>>>(w_proj, wprojT, D_, D_);
  // QKV GEMM with fused V-transpose epilogue (V -> Vg; Q,K -> qkv_bf)
  gemm_bt_mfma<true><<<dim3(D3_ / GBN, M / GBM), 256, 0, stream>>>(
      xb, wattnT, b_attn, qkv_bf, Vg, M, D3_, D_);
  attn_fwd_mfma<<<dim3(T_ / QBLK * B_ * H_), 256, 0, stream>>>(qkv_bf, Vg, y_bf);
  gemm_bt_mfma<false><<<dim3(D_ / GBN, M / GBM), 256, 0, stream>>>(
      y_bf, wprojT, b_proj, out, nullptr, M, D_, D_);
}

// Round 15
// 177.554 us; speedup vs baseline: 1.0514x; 1.0438x over previous
//
#include <hip/hip_runtime.h>
#include <math.h>

typedef __bf16 bf16_t;
typedef __attribute__((ext_vector_type(8))) __bf16 bf16x8;
typedef __attribute__((ext_vector_type(4))) float f32x4;

#define B_  4
#define T_  2048
#define D_  1024
#define H_  16
#define HD_ 64
#define D3_ 3072

__device__ __forceinline__ void load_lds16(const bf16_t* g, char* lds) {
  __builtin_amdgcn_global_load_lds(
      (const __attribute__((address_space(1))) void*)g,
      (__attribute__((address_space(3))) void*)lds, 16, 0, 0);
}

// ---------------------------------------------------------------------------
// fp32 -> bf16 elementwise convert (vectorized)
// ---------------------------------------------------------------------------
__global__ __launch_bounds__(256) void convert_bf16(
    const float* __restrict__ in, bf16_t* __restrict__ out, int n4) {
  int idx = blockIdx.x * 256 + threadIdx.x;
  int stride = gridDim.x * 256;
  for (int i = idx; i < n4; i += stride) {
    float4 v = ((const float4*)in)[i];
    alignas(8) bf16_t o4[4] = {(bf16_t)v.x, (bf16_t)v.y, (bf16_t)v.z, (bf16_t)v.w};
    ((uint2*)out)[i] = *(const uint2*)o4;
  }
}

// ---------------------------------------------------------------------------
// Both weights (K x N fp32) -> (N x K bf16) in ONE launch.
// by < 48: w_attn (N=3072); else w_proj (N=1024). K=1024 for both.
// ---------------------------------------------------------------------------
__global__ __launch_bounds__(256) void transpose_convert2(
    const float* __restrict__ Wa, bf16_t* __restrict__ Wat,
    const float* __restrict__ Wp, bf16_t* __restrict__ Wpt) {
  __shared__ float tile[64][65];
  int by = blockIdx.y;
  const float* W;
  bf16_t* Wt;
  int N;
  if (by < 48) {
    W = Wa; Wt = Wat; N = D3_;
  } else {
    W = Wp; Wt = Wpt; N = D_; by -= 48;
  }
  const int K = D_;
  const int k0 = blockIdx.x * 64, n0 = by * 64;
  const int tid = threadIdx.x;
  const int r = tid >> 4, c4 = (tid & 15) * 4;
#pragma unroll
  for (int i = 0; i < 4; ++i) {
    float4 v = *(const float4*)(W + (size_t)(k0 + r + i * 16) * N + n0 + c4);
    tile[r + i * 16][c4 + 0] = v.x;
    tile[r + i * 16][c4 + 1] = v.y;
    tile[r + i * 16][c4 + 2] = v.z;
    tile[r + i * 16][c4 + 3] = v.w;
  }
  __syncthreads();
#pragma unroll
  for (int i = 0; i < 4; ++i) {
    int n = r + i * 16;
    alignas(8) bf16_t o4[4];
#pragma unroll
    for (int j = 0; j < 4; ++j) o4[j] = (bf16_t)tile[c4 + j][n];
    *(uint2*)(Wt + (size_t)(n0 + n) * K + k0 + c4) = *(const uint2*)o4;
  }
}

// ---------------------------------------------------------------------------
// bf16 MFMA GEMM (128x128, 2-phase dbuf) — proven structure (R5/R12).
// R15: 1D grid + bijective XCD swizzle (T1; grid % 8 == 0 for both calls):
// block orig lands on XCD orig%8 and computes tile swz=(orig%8)*cpx+orig/8,
// so each XCD owns a contiguous slab of block-rows (B-panel L2 reuse).
// ---------------------------------------------------------------------------
#define GBM 128
#define GBN 128
#define GBK 32

template <bool BF16_OUT>
__global__ __launch_bounds__(256) void gemm_bt_mfma(
    const bf16_t* __restrict__ A, const bf16_t* __restrict__ Bt,
    const float* __restrict__ bias, void* __restrict__ Cv,
    int M, int N, int K) {
  __shared__ __align__(16) bf16_t Asl[2][GBM * GBK];
  __shared__ __align__(16) bf16_t Bsl[2][GBN * GBK];

  const int tid = threadIdx.x;
  const int w = tid >> 6, l = tid & 63;
  const int l15 = l & 15, lhi = l >> 4;

  // XCD-aware bijective remap (gridDim.x % 8 == 0)
  const int nbx = N / GBN;
  const int cpx = gridDim.x >> 3;
  const int swz = (blockIdx.x & 7) * cpx + (blockIdx.x >> 3);
  const int row0 = (swz / nbx) * GBM, col0 = (swz % nbx) * GBN;
  const int wr = (w >> 1) * 64, wc = (w & 1) * 64;

  const int srow = tid >> 2;
  const int sf = (srow & 3) ^ ((srow >> 2) & 3);
  const int slog = (tid & 3) ^ sf;
  const int rf = (l15 & 3) ^ ((l15 >> 2) & 3);
  const int rchunk = lhi ^ rf;

  f32x4 acc[4][4];
#pragma unroll
  for (int i = 0; i < 4; ++i)
#pragma unroll
    for (int j = 0; j < 4; ++j) acc[i][j] = (f32x4){0.f, 0.f, 0.f, 0.f};

  const bf16_t* Abase = A + (size_t)row0 * K;
  const bf16_t* Bbase = Bt + (size_t)col0 * K;

  auto stage = [&](int buf, int k0) {
#pragma unroll
    for (int issue = 0; issue < 2; ++issue) {
      const bf16_t* ga = Abase + (size_t)(issue * 64 + srow) * K + k0 + slog * 8;
      load_lds16(ga, (char*)&Asl[buf][0] + issue * 4096 + w * 1024);
      const bf16_t* gb = Bbase + (size_t)(issue * 64 + srow) * K + k0 + slog * 8;
      load_lds16(gb, (char*)&Bsl[buf][0] + issue * 4096 + w * 1024);
    }
  };

  const int nt = K / GBK;
  stage(0, 0);

  for (int t = 0; t < nt; ++t) {
    __syncthreads();
    if (t + 1 < nt) stage((t + 1) & 1, (t + 1) * GBK);

    const bf16_t* As = &Asl[t & 1][0];
    const bf16_t* Bs = &Bsl[t & 1][0];
    bf16x8 af[4], bf[4];
#pragma unroll
    for (int i = 0; i < 4; ++i)
      af[i] = *(const bf16x8*)&As[(wr + i * 16 + l15) * GBK + rchunk * 8];
#pragma unroll
    for (int j = 0; j < 4; ++j)
      bf[j] = *(const bf16x8*)&Bs[(wc + j * 16 + l15) * GBK + rchunk * 8];
#pragma unroll
    for (int i = 0; i < 4; ++i)
#pragma unroll
      for (int j = 0; j < 4; ++j)
        acc[i][j] =
            __builtin_amdgcn_mfma_f32_16x16x32_bf16(af[i], bf[j], acc[i][j], 0, 0, 0);
  }

  // epilogue: C/D layout col=l&15, row=(l>>4)*4+reg
#pragma unroll
  for (int j = 0; j < 4; ++j) {
    int colr = col0 + wc + j * 16 + l15;
    float bv = bias[colr];
#pragma unroll
    for (int i = 0; i < 4; ++i) {
#pragma unroll
      for (int r = 0; r < 4; ++r) {
        int rowr = row0 + wr + i * 16 + lhi * 4 + r;
        float val = acc[i][j][r] + bv;
        if constexpr (BF16_OUT)
          ((bf16_t*)Cv)[(size_t)rowr * N + colr] = (bf16_t)val;
        else
          ((float*)Cv)[(size_t)rowr * N + colr] = val;
      }
    }
  }
}

// ---------------------------------------------------------------------------
// Transpose V out of qkv_bf into Vg[bh][d][t] (bf16).  (R12 form)
// ---------------------------------------------------------------------------
__global__ __launch_bounds__(256) void transpose_v(
    const bf16_t* __restrict__ qkv, bf16_t* __restrict__ Vg) {
  const int bh = blockIdx.y;
  const int b = bh >> 4, h = bh & 15;
  const int t0 = blockIdx.x * 64;
  const int tid = threadIdx.x;
  const int d = tid & 63;
  const int w = tid >> 6;
  alignas(16) bf16_t tmp[16];
#pragma unroll
  for (int j = 0; j < 16; ++j) {
    int t = t0 + w * 16 + j;
    tmp[j] = qkv[(size_t)(b * T_ + t) * D3_ + 2 * D_ + h * HD_ + d];
  }
  bf16_t* dst = Vg + (size_t)(bh * HD_ + d) * T_ + t0 + w * 16;
  *(uint4*)(dst) = *(const uint4*)(tmp);
  *(uint4*)(dst + 8) = *(const uint4*)(tmp + 8);
}

// ---------------------------------------------------------------------------
// Causal flash attention (R12 form, unchanged): swapped-QK^T 16x16x32 MFMA,
// 4 waves / QBLK=128, 2-barrier staged loop, fixed-max softmax (c=8).
// ---------------------------------------------------------------------------
#define QBLK 128
#define KBLK 64

__global__ __launch_bounds__(256, 4) void attn_fwd_mfma(
    const bf16_t* __restrict__ qkv, const bf16_t* __restrict__ Vg,
    bf16_t* __restrict__ y) {
  const int lin = blockIdx.x;
  const int bh = (lin & 7) * 8 + ((lin >> 3) & 7);  // XCD-local heads
  const int qt = (T_ / QBLK - 1) - (lin >> 6);      // tail-first
  const int b = bh >> 4, h = bh & 15;
  const int Q0 = qt * QBLK;
  const int tid = threadIdx.x;
  const int w = tid >> 6, l = tid & 63;
  const int l15 = l & 15, lhi = l >> 4;

  __shared__ __align__(16) bf16_t K_lds[2][KBLK * 64];
  __shared__ __align__(16) bf16_t V_lds[KBLK * 64];
  __shared__ __align__(16) bf16_t P_lds[4][16][72];

  const int sr = tid >> 3, sp = tid & 7;
  const int slc = sp ^ (sr & 7);
  const int swz = (l15 & 7);

  auto stageK = [&](int buf, int kt) {
    const bf16_t* src =
        qkv + (size_t)(b * T_ + kt * KBLK + sr) * D3_ + D_ + h * HD_ + slc * 8;
    char* dst = (char*)(&K_lds[buf][0]) + w * 1024;
    load_lds16(src, dst);
    load_lds16(src + (size_t)32 * D3_, dst + 4096);
  };
  auto stageV = [&](int kt) {
    const bf16_t* src = Vg + ((size_t)bh * HD_ + sr) * T_ + kt * KBLK + slc * 8;
    char* dst = (char*)(&V_lds[0]) + w * 1024;
    load_lds16(src, dst);
    load_lds16(src + (size_t)32 * T_, dst + 4096);
  };

  bf16x8 qf[2][2];
#pragma unroll
  for (int g = 0; g < 2; ++g) {
    int q = Q0 + w * 32 + g * 16 + l15;
#pragma unroll
    for (int c = 0; c < 2; ++c) {
      const bf16_t* p = qkv + (size_t)(b * T_ + q) * D3_ + h * HD_ + c * 32 + lhi * 8;
      bf16x8 v = *(const bf16x8*)p;
#pragma unroll
      for (int e = 0; e < 8; ++e) v[e] = (bf16_t)((float)v[e] * 0.125f);
      qf[g][c] = v;
    }
  }

  f32x4 accO[2][4];
#pragma unroll
  for (int g = 0; g < 2; ++g)
#pragma unroll
    for (int dg = 0; dg < 4; ++dg) accO[g][dg] = (f32x4){0.f, 0.f, 0.f, 0.f};
  float lsum[2] = {0.f, 0.f};
  const float FMAX = 8.f;

  const int ntiles = Q0 / KBLK + 2;
  const int qg0 = Q0 + w * 32;
  const int qg1 = qg0 + 16;

  stageK(0, 0);
  __syncthreads();

  for (int kt = 0; kt < ntiles; ++kt) {
    const int cur = kt & 1;
    const int ktb = kt * KBLK;
    stageV(kt);
    if (kt + 1 < ntiles) stageK(cur ^ 1, kt + 1);

    const bool act0 = (ktb <= qg0 + 15);
    const bool act1 = (ktb <= qg1 + 15);
    uint2 pp1[4];

#pragma unroll
    for (int g = 0; g < 2; ++g) {
      if (!(g == 0 ? act0 : act1)) continue;
      const int qg = g == 0 ? qg0 : qg1;

      f32x4 s[4];
#pragma unroll
      for (int n = 0; n < 4; ++n) s[n] = (f32x4){0.f, 0.f, 0.f, 0.f};
      __builtin_amdgcn_s_setprio(1);
#pragma unroll
      for (int c = 0; c < 2; ++c) {
#pragma unroll
        for (int n = 0; n < 4; ++n) {
          bf16x8 kf = *(const bf16x8*)&K_lds[cur][(n * 16 + l15) * 64 +
                                                 (((c * 4 + lhi) ^ swz) * 8)];
          s[n] = __builtin_amdgcn_mfma_f32_16x16x32_bf16(kf, qf[g][c], s[n], 0, 0, 0);
        }
      }
      __builtin_amdgcn_s_setprio(0);

      if (ktb + KBLK - 1 > qg) {
        const int qml = qg + l15 - ktb - lhi * 4;
#pragma unroll
        for (int n = 0; n < 4; ++n)
#pragma unroll
          for (int r = 0; r < 4; ++r)
            if (n * 16 + r > qml) s[n][r] = -INFINITY;
      }

      float rowsum = 0.f;
#pragma unroll
      for (int n = 0; n < 4; ++n) {
        alignas(8) bf16_t p4[4];
#pragma unroll
        for (int r = 0; r < 4; ++r) {
          float p = __expf(s[n][r] - FMAX);
          rowsum += p;
          p4[r] = (bf16_t)p;
        }
        if (g == 0)
          *(uint2*)&P_lds[w][l15][n * 16 + lhi * 4] = *(const uint2*)p4;
        else
          pp1[n] = *(const uint2*)p4;
      }
      lsum[g] += rowsum;
    }

    __syncthreads();

    if (act0) {
      __builtin_amdgcn_s_setprio(1);
#pragma unroll
      for (int c2 = 0; c2 < 2; ++c2) {
        bf16x8 pf = *(const bf16x8*)&P_lds[w][l15][c2 * 32 + lhi * 8];
#pragma unroll
        for (int dg = 0; dg < 4; ++dg) {
          bf16x8 vf = *(const bf16x8*)&V_lds[(dg * 16 + l15) * 64 +
                                             (((c2 * 4 + lhi) ^ swz) * 8)];
          accO[0][dg] =
              __builtin_amdgcn_mfma_f32_16x16x32_bf16(pf, vf, accO[0][dg], 0, 0, 0);
        }
      }
      __builtin_amdgcn_s_setprio(0);
    }
    if (act1) {
#pragma unroll
      for (int n = 0; n < 4; ++n)
        *(uint2*)&P_lds[w][l15][n * 16 + lhi * 4] = pp1[n];
      __builtin_amdgcn_s_setprio(1);
#pragma unroll
      for (int c2 = 0; c2 < 2; ++c2) {
        bf16x8 pf = *(const bf16x8*)&P_lds[w][l15][c2 * 32 + lhi * 8];
#pragma unroll
        for (int dg = 0; dg < 4; ++dg) {
          bf16x8 vf = *(const bf16x8*)&V_lds[(dg * 16 + l15) * 64 +
                                             (((c2 * 4 + lhi) ^ swz) * 8)];
          accO[1][dg] =
              __builtin_amdgcn_mfma_f32_16x16x32_bf16(pf, vf, accO[1][dg], 0, 0, 0);
        }
      }
      __builtin_amdgcn_s_setprio(0);
    }

    __syncthreads();
  }

#pragma unroll
  for (int g = 0; g < 2; ++g) {
    float ls = lsum[g];
    ls += __shfl_xor(ls, 16);
    ls += __shfl_xor(ls, 32);
#pragma unroll
    for (int r = 0; r < 4; ++r) {
      float lr = __shfl(ls, lhi * 4 + r);
      float inv = 1.f / lr;
      int q = Q0 + w * 32 + g * 16 + lhi * 4 + r;
      bf16_t* yr = y + (size_t)(b * T_ + q) * D_ + h * HD_ + l15;
#pragma unroll
      for (int dg = 0; dg < 4; ++dg) yr[dg * 16] = (bf16_t)(accO[g][dg][r] * inv);
    }
  }
}

// ---------------------------------------------------------------------------
extern "C" void kernel_launch(void* const* d_in, const int* in_sizes, int n_in,
                              void* d_out, int out_size, void* d_ws, size_t ws_size,
                              hipStream_t stream) {
  const float* x      = (const float*)d_in[0];
  const float* w_attn = (const float*)d_in[1];
  const float* b_attn = (const float*)d_in[2];
  const float* w_proj = (const float*)d_in[3];
  const float* b_proj = (const float*)d_in[4];
  float* out = (float*)d_out;

  const int M = B_ * T_;  // 8192

  bf16_t* xb      = (bf16_t*)d_ws;                         // 16 MB (reused as y_bf)
  bf16_t* wattnT  = xb + (size_t)M * D_;                   // 6 MB
  bf16_t* wprojT  = wattnT + (size_t)D3_ * D_;             // 2 MB
  bf16_t* qkv_bf  = wprojT + (size_t)D_ * D_;              // 48 MB
  bf16_t* Vg      = qkv_bf + (size_t)M * D3_;              // 16 MB
  bf16_t* y_bf    = xb;

  convert_bf16<<<2048, 256, 0, stream>>>(x, xb, M * D_ / 4);
  // both weight transposes in one launch
  transpose_convert2<<<dim3(D_ / 64, 64), 256, 0, stream>>>(
      w_attn, wattnT, w_proj, wprojT);
  // QKV GEMM (1536 blocks, XCD-swizzled)
  gemm_bt_mfma<true><<<(D3_ / GBN) * (M / GBM), 256, 0, stream>>>(
      xb, wattnT, b_attn, qkv_bf, M, D3_, D_);
  transpose_v<<<dim3(T_ / 64, B_ * H_), 256, 0, stream>>>(qkv_bf, Vg);
  attn_fwd_mfma<<<dim3(T_ / QBLK * B_ * H_), 256, 0, stream>>>(qkv_bf, Vg, y_bf);
  // proj GEMM (512 blocks, XCD-swizzled)
  gemm_bt_mfma<false><<<(D_ / GBN) * (M / GBM), 256, 0, stream>>>(
      y_bf, wprojT, b_proj, out, M, D_, D_);
}